// Round 11
// baseline (129.339 us; speedup 1.0000x reference)
//
#include <hip/hip_runtime.h>
#include <math.h>

// Problem constants (from reference)
#define BB 16
#define NN 65536
#define DD 8
#define OUT_SIZE 4096
#define IN_SIZE 4096

#define BLOCKS_PER_B 16
#define NC (NN / BLOCKS_PER_B)     // 4096 tuples per block
#define BLOCK_THREADS 1024         // 16 waves/block
#define TPT (NC / BLOCK_THREADS)   // 4 tuples per thread, 2-deep pipelined

// y[b,o] = bias[o]  (output is re-poisoned before every timed launch)
__global__ void init_out(const float* __restrict__ bias, float* __restrict__ y) {
    int i = blockIdx.x * blockDim.x + threadIdx.x;     // 0 .. B*OUT_SIZE-1
    y[i] = bias[i & (OUT_SIZE - 1)];
}

struct TupIn {
    float4 nz[4];
    float2 mean;
    float  sigma, value;
};

__device__ __forceinline__ void load_tuple(TupIn& T,
                                           const float* __restrict__ means,
                                           const float* __restrict__ sigmas,
                                           const float* __restrict__ values,
                                           const float* __restrict__ noise,
                                           size_t idx) {
    T.mean  = ((const float2*)means)[idx];
    T.sigma = sigmas[idx];
    T.value = values[idx];
    const float4* np4 = (const float4*)(noise + idx * (size_t)(DD * 2));
    T.nz[0] = np4[0]; T.nz[1] = np4[1]; T.nz[2] = np4[2]; T.nz[3] = np4[3];
}

__global__ __launch_bounds__(BLOCK_THREADS, 4)
void hyper_scatter(const float* __restrict__ x,
                   const float* __restrict__ means,
                   const float* __restrict__ sigmas,
                   const float* __restrict__ values,
                   const float* __restrict__ noise,
                   float* __restrict__ y) {
    __shared__ float ys[OUT_SIZE];   // per-(b,chunk) partial output, 16 KB
    __shared__ float xs[IN_SIZE];    // staged x[b,:], 16 KB

    const int b     = blockIdx.x >> 4;          // blockIdx / BLOCKS_PER_B
    const int chunk = blockIdx.x & (BLOCKS_PER_B - 1);
    const int tid   = threadIdx.x;
    const float* xb = x + (size_t)b * IN_SIZE;

    // zero partial accumulator + stage x[b] (1024 threads, 1 float4 each)
    ((float4*)ys)[tid] = make_float4(0.f, 0.f, 0.f, 0.f);
    ((float4*)xs)[tid] = ((const float4*)xb)[tid];
    __syncthreads();

    const size_t tb = (size_t)b * NN + (size_t)chunk * NC;

    // ---- 2-deep rolling software pipeline over 4 tuples/thread ----
    TupIn cur, nxt;
    load_tuple(cur, means, sigmas, values, noise, tb + tid);

    #pragma unroll
    for (int t = 0; t < TPT; ++t) {
        // issue next batch's loads BEFORE computing this batch: the whole
        // compute phase (~300 VALU ops) covers the load latency.
        if (t + 1 < TPT)
            load_tuple(nxt, means, sigmas, values, noise,
                       tb + (size_t)(t + 1) * BLOCK_THREADS + tid);

        const float nr[DD * 2] = {
            cur.nz[0].x, cur.nz[0].y, cur.nz[0].z, cur.nz[0].w,
            cur.nz[1].x, cur.nz[1].y, cur.nz[1].z, cur.nz[1].w,
            cur.nz[2].x, cur.nz[2].y, cur.nz[2].z, cur.nz[2].w,
            cur.nz[3].x, cur.nz[3].y, cur.nz[3].z, cur.nz[3].w };

        // exp(q * -1/(2s^2)) == exp2(q * c2), c2 folded once per tuple
        const float c2 = (-0.5f * 1.44269504088896f) / (cur.sigma * cur.sigma);

        float p[DD];
        int   oi[DD], ii[DD];
        float psum = 0.f;
        #pragma unroll
        for (int d = 0; d < DD; ++d) {
            // EXACT sample rounding: mul-then-add, no FMA contraction,
            // so rintf() flips the same half-integer cases as np.round.
            float s0 = __fadd_rn(__fmul_rn(nr[2 * d],     cur.sigma), cur.mean.x);
            float s1 = __fadd_rn(__fmul_rn(nr[2 * d + 1], cur.sigma), cur.mean.y);
            float d0 = s0 - cur.mean.x;         // reference's diff (post-roundtrip)
            float d1 = s1 - cur.mean.y;
            float q  = d0 * d0 + d1 * d1;
            float pd = exp2f(q * c2);           // 1/(2πσ²) cancels in normalization
            p[d] = pd;
            psum += pd;
            oi[d] = (int)fminf(fmaxf(rintf(s0), 0.f), (float)(OUT_SIZE - 1));
            ii[d] = (int)fminf(fmaxf(rintf(s1), 0.f), (float)(IN_SIZE - 1));
        }
        // fast reciprocal (~1 ulp) instead of full-precision divide
        const float wscale = cur.value * __builtin_amdgcn_rcpf(psum);

        // gathers pipe-split: even slots -> LDS (DS pipe), odd -> global
        // (TA/L1 pipe; x[b] is 16 KB, cache-resident). All 8 issued together.
        float xv[DD];
        #pragma unroll
        for (int d = 0; d < DD; ++d)
            xv[d] = (d & 1) ? xb[ii[d]] : xs[ii[d]];

        float v[DD];
        #pragma unroll
        for (int d = 0; d < DD; ++d) v[d] = p[d] * xv[d];

        // ---- relaxed oi-merge: add each later v[d] into ALL earlier slots
        // with the same oi. v[d] is pristine when processed (only j<d are
        // ever modified), so the FIRST occurrence of each oi accumulates
        // every original contribution exactly once; intermediate dup slots
        // get polluted but never scatter (dupO). No deadO dependency chain.
        bool dupO[DD];
        dupO[0] = false;
        #pragma unroll
        for (int d = 1; d < DD; ++d) {
            bool any = false;
            #pragma unroll
            for (int j = 0; j < d; ++j) {
                bool m = (oi[j] == oi[d]);
                if (m) v[j] += v[d];
                any = any || m;
            }
            dupO[d] = any;
        }

        // one LDS atomic per UNIQUE oi (~4.8 of 8)
        #pragma unroll
        for (int d = 0; d < DD; ++d) {
            if (!dupO[d]) atomicAdd(&ys[oi[d]], wscale * v[d]);
        }

        cur = nxt;
    }
    __syncthreads();

    // one HW fp atomic per output element per block (coalesced, cheap)
    float* yb = y + (size_t)b * OUT_SIZE;
    #pragma unroll
    for (int o = tid; o < OUT_SIZE; o += BLOCK_THREADS) {
        unsafeAtomicAdd(&yb[o], ys[o]);
    }
}

extern "C" void kernel_launch(void* const* d_in, const int* in_sizes, int n_in,
                              void* d_out, int out_size, void* d_ws, size_t ws_size,
                              hipStream_t stream) {
    const float* x      = (const float*)d_in[0];   // [B, IN_SIZE]
    const float* means  = (const float*)d_in[1];   // [B, N, 2]
    const float* sigmas = (const float*)d_in[2];   // [B, N]
    const float* values = (const float*)d_in[3];   // [B, N]
    const float* bias   = (const float*)d_in[4];   // [OUT_SIZE]
    const float* noise  = (const float*)d_in[5];   // [B, N, D, 2]
    float* y = (float*)d_out;                      // [B, OUT_SIZE]

    init_out<<<(BB * OUT_SIZE) / 256, 256, 0, stream>>>(bias, y);
    hyper_scatter<<<BB * BLOCKS_PER_B, BLOCK_THREADS, 0, stream>>>(
        x, means, sigmas, values, noise, y);
}